// Round 2
// baseline (13873.814 us; speedup 1.0000x reference)
//
#include <hip/hip_runtime.h>
#include <stdint.h>

namespace {
constexpr int kB = 64, kT = 200;
constexpr int kNin = 700, kNs = 50, kNz = 100, kNh = 512, kNho = 100, kNout = 20;
constexpr float kDecay = 0.95f, kThresh = 0.5f, kRefrac = 2.0f;
}

// Adaptive-LIF update (REST=RESET=0, DT=1).
__device__ __forceinline__ void lif(float& v, float& r, float x, bool& spk) {
    r = fmaxf(r - 1.0f, 0.0f);
    v = kDecay * v + (r <= 0.0f ? x : 0.0f);
    spk = (v >= kThresh);
    if (spk) { v = 0.0f; r = kRefrac; }
}

// Deterministic sparse row-sum: sum_{i in lst[0..cnt)} W[i*ld + j]
__device__ __forceinline__ float rowsum(const unsigned short* lst, int cnt,
                                        const float* __restrict__ W, int ld, int j) {
    float a0 = 0.f, a1 = 0.f, a2 = 0.f, a3 = 0.f;
    int q = 0;
    for (; q + 4 <= cnt; q += 4) {
        const int i0 = lst[q], i1 = lst[q + 1], i2 = lst[q + 2], i3 = lst[q + 3];
        a0 += W[i0 * ld + j];
        a1 += W[i1 * ld + j];
        a2 += W[i2 * ld + j];
        a3 += W[i3 * ld + j];
    }
    for (; q < cnt; ++q) a0 += W[lst[q] * ld + j];
    return (a0 + a1) + (a2 + a3);
}

__global__ __launch_bounds__(1024, 1)
void snn_seq(const float* __restrict__ x_in, const float* __restrict__ W_i,
             const float* __restrict__ W_z, const float* __restrict__ W_c,
             const float* __restrict__ W_h, const float* __restrict__ W_ho,
             const float* __restrict__ W_o, const float* __restrict__ lam_p,
             const float* __restrict__ eta_p, float* __restrict__ out) {
    __shared__ unsigned long long hist[kT][8];          // 12800 B: h spike history
    __shared__ float xi[kT * kNs];                      // 40000 B: precomputed x@W_i
    __shared__ float lampow[kT];                        // 800
    __shared__ float ck[kT];                            // 800
    __shared__ __align__(16) float prevh[kNh];          // 2048: h_new state
    __shared__ float fpart[kNh];                        // 2048: dense-matvec K-half partial
    __shared__ float hpart[kNh];                        // 2048: recall/rowsum partial
    __shared__ float ho_red[8][kNho];                   // 3200: h_new@W_ho partials
    __shared__ unsigned short idx_s[kNs], idx_z[kNz], idx_h[kNh], idx_o[kNho];
    __shared__ int cnt_z, cnt_h;

    const int tid = threadIdx.x;
    const int lane = tid & 63;
    const int wave = tid >> 6;
    const int q = tid >> 9;        // K-half / role split
    const int j = tid & 511;       // neuron index within h population
    const int b = blockIdx.x;
    const float lam = lam_p[0], eta = eta_p[0];

    // ---- prologue: lampow, prevh=0, xi = x@W_i for all t (register-tiled) ----
    if (tid == 0) {
        float p = 1.0f;
        for (int i = 0; i < kT; ++i) { lampow[i] = p; p *= lam; }
    }
    if (tid < kNh) prevh[tid] = 0.0f;
    if (tid < 1000) {
        const int jj = tid % kNs;          // output col 0..49
        const int tslot = tid / kNs;       // 0..19; covers t = tslot + 20*r
        const float* wcol = W_i + jj;
        const float* x0 = x_in + ((size_t)tslot * kB + b) * kNin;
        const size_t stride20 = (size_t)20 * kB * kNin;
        float a0 = 0, a1 = 0, a2 = 0, a3 = 0, a4 = 0, a5 = 0, a6 = 0, a7 = 0, a8 = 0, a9 = 0;
        for (int i = 0; i < kNin; ++i) {
            const float w = wcol[i * kNs];
            a0 = fmaf(x0[i], w, a0);
            a1 = fmaf(x0[stride20 + i], w, a1);
            a2 = fmaf(x0[2 * stride20 + i], w, a2);
            a3 = fmaf(x0[3 * stride20 + i], w, a3);
            a4 = fmaf(x0[4 * stride20 + i], w, a4);
            a5 = fmaf(x0[5 * stride20 + i], w, a5);
            a6 = fmaf(x0[6 * stride20 + i], w, a6);
            a7 = fmaf(x0[7 * stride20 + i], w, a7);
            a8 = fmaf(x0[8 * stride20 + i], w, a8);
            a9 = fmaf(x0[9 * stride20 + i], w, a9);
        }
        xi[(tslot + 0) * kNs + jj] = a0;
        xi[(tslot + 20) * kNs + jj] = a1;
        xi[(tslot + 40) * kNs + jj] = a2;
        xi[(tslot + 60) * kNs + jj] = a3;
        xi[(tslot + 80) * kNs + jj] = a4;
        xi[(tslot + 100) * kNs + jj] = a5;
        xi[(tslot + 120) * kNs + jj] = a6;
        xi[(tslot + 140) * kNs + jj] = a7;
        xi[(tslot + 160) * kNs + jj] = a8;
        xi[(tslot + 180) * kNs + jj] = a9;
    }

    // LIF states (live only in owner lanes)
    float vs = 0, rs = 0;                         // wave 15, lane<50
    float vz0 = 0, rz0 = 0, vz1 = 0, rz1 = 0;     // wave 15
    float vh = 0, rh = 0;                         // q==0 (thread j)
    float vo0 = 0, ro0 = 0, vo1 = 0, ro1 = 0;     // wave 0
    float vy = 0, ry = 0;                         // wave 0, lane<20
    float czv = 0, facc = 0, hreg = 0;

    __syncthreads();

    for (int t = 0; t < kT; ++t) {
        // ---- S7 (wave 0): o-LIF + y-LIF epilogue of step t-1 (overlaps F) ----
        if (wave == 0 && t > 0) {
            float oa0 = 0, oa1 = 0;
#pragma unroll
            for (int g = 0; g < 8; ++g) {
                oa0 += ho_red[g][lane];
                if (lane < 36) oa1 += ho_red[g][64 + lane];
            }
            bool o0 = false, o1 = false;
            lif(vo0, ro0, oa0, o0);
            if (lane < 36) lif(vo1, ro1, oa1, o1);
            const unsigned long long om0 = __ballot(o0);
            const unsigned long long om1 = __ballot(o1);
            if (o0) idx_o[__popcll(om0 & ((1ull << lane) - 1))] = (unsigned short)lane;
            if (o1) idx_o[__popcll(om0) + __popcll(om1 & ((1ull << lane) - 1))] =
                (unsigned short)(64 + lane);
            const int co = __popcll(om0) + __popcll(om1);
            if (lane < kNout) {
                const float yx = rowsum(idx_o, co, W_o, kNout, lane);
                bool ys = false;
                lif(vy, ry, yx, ys);
                out[((size_t)(t - 1) * kB + b) * kNout + lane] = ys ? 1.0f : 0.0f;
            }
        }
        // ---- S1 (wave 15): s-LIF + z-LIF + index lists (overlaps F) ----
        if (wave == 15) {
            bool sspk = false;
            if (lane < kNs) {
                const float sx = xi[t * kNs + lane];
                lif(vs, rs, sx, sspk);
            }
            const unsigned long long sm = __ballot(sspk);
            if (sspk) idx_s[__popcll(sm & ((1ull << lane) - 1))] = (unsigned short)lane;
            const int cs = __popcll(sm);
            bool z0 = false, z1 = false;
            const float zx0 = rowsum(idx_s, cs, W_z, kNz, lane);
            lif(vz0, rz0, zx0, z0);
            if (lane < 36) {
                const float zx1 = rowsum(idx_s, cs, W_z, kNz, 64 + lane);
                lif(vz1, rz1, zx1, z1);
            }
            const unsigned long long zm0 = __ballot(z0);
            const unsigned long long zm1 = __ballot(z1);
            if (z0) idx_z[__popcll(zm0 & ((1ull << lane) - 1))] = (unsigned short)lane;
            if (z1) idx_z[__popcll(zm0) + __popcll(zm1 & ((1ull << lane) - 1))] =
                (unsigned short)(64 + lane);
            if (lane == 0) cnt_z = __popcll(zm0) + __popcll(zm1);
        }
        // ---- F (all): dense prevh @ W_h, split-K halves of 256 ----
        {
            const float* wh = W_h + j;
            const int k0 = q << 8;
            float a0 = 0.f, a1 = 0.f, a2 = 0.f, a3 = 0.f;
            for (int k = k0; k < k0 + 256; k += 8) {
                const float4 p0 = *(const float4*)&prevh[k];
                const float4 p1 = *(const float4*)&prevh[k + 4];
                a0 = fmaf(p0.x, wh[(k + 0) * kNh], a0);
                a1 = fmaf(p0.y, wh[(k + 1) * kNh], a1);
                a2 = fmaf(p0.z, wh[(k + 2) * kNh], a2);
                a3 = fmaf(p0.w, wh[(k + 3) * kNh], a3);
                a0 = fmaf(p1.x, wh[(k + 4) * kNh], a0);
                a1 = fmaf(p1.y, wh[(k + 5) * kNh], a1);
                a2 = fmaf(p1.z, wh[(k + 6) * kNh], a2);
                a3 = fmaf(p1.w, wh[(k + 7) * kNh], a3);
            }
            facc = (a0 + a1) + (a2 + a3);
            if (q) fpart[j] = facc;
        }
        __syncthreads();  // bar1

        // ---- S2 (q==0): cz rowsum + combine + h-LIF + history ballot ----
        bool hspk = false;
        if (q == 0) {
            czv = rowsum(idx_z, cnt_z, W_c, kNh, j);
            const float tot = facc + fpart[j] + czv;
            lif(vh, rh, tot, hspk);
        }
        {
            const unsigned long long hm = __ballot(hspk);
            if (q == 0 && lane == 0) hist[t][wave] = hm;
        }
        __syncthreads();  // bar2

        // ---- S3: recall coefficients ck + h index list ----
        if (tid <= t) {
            const unsigned long long* ht = hist[t];
            const unsigned long long* hk = hist[tid];
            int d = 0;
#pragma unroll
            for (int w = 0; w < 8; ++w) d += __popcll(ht[w] & hk[w]);
            ck[tid] = eta * lampow[t - tid] * (float)d;
        }
        if (q == 0) {
            const unsigned long long mw = hist[t][wave];
            if ((mw >> lane) & 1) {
                int pos = __popcll(mw & ((1ull << lane) - 1));
                for (int u = 0; u < wave; ++u) pos += __popcll(hist[t][u]);
                idx_h[pos] = (unsigned short)j;
            }
            if (tid == 0) {
                int c = 0;
#pragma unroll
                for (int u = 0; u < 8; ++u) c += __popcll(hist[t][u]);
                cnt_h = c;
            }
        }
        __syncthreads();  // bar3

        // ---- S4 (all): split sparse h@W_h rowsum + split recall loop ----
        {
            const int ch = cnt_h;
            const int ch2 = ch >> 1;
            const int half = (t + 1) >> 1;
            const int rlo = q ? ch2 : 0;
            const int rn = q ? (ch - ch2) : ch2;
            const int klo = q ? half : 0;
            const int khi = q ? (t + 1) : half;
            float part = rowsum(idx_h + rlo, rn, W_h, kNh, j);
            const int w = j >> 6, bit = j & 63;
            float racc = 0.f;
            for (int k = klo; k < khi; ++k) {
                const float c = ck[k];
                racc += ((hist[k][w] >> bit) & 1) ? c : 0.f;
            }
            part += racc;
            if (q) hpart[j] = part; else hreg = part;
        }
        __syncthreads();  // bar4

        // ---- S5 (q==0): h_new = hw + cz + recall ----
        if (q == 0) prevh[j] = hreg + hpart[j] + czv;
        __syncthreads();  // bar5

        // ---- S6: h_new @ W_ho partials (8 groups of 64 rows x 100 cols) ----
        if (tid < 800) {
            const int g = tid / kNho, j2 = tid - g * kNho;
            const float* wp = W_ho + j2;
            float s0 = 0.f, s1 = 0.f;
            const int i0 = g * 64;
            for (int i = i0; i < i0 + 64; i += 2) {
                s0 = fmaf(prevh[i], wp[i * kNho], s0);
                s1 = fmaf(prevh[i + 1], wp[(i + 1) * kNho], s1);
            }
            ho_red[g][j2] = s0 + s1;
        }
        __syncthreads();  // bar6
    }

    // ---- final epilogue for t = kT-1 ----
    if (wave == 0) {
        float oa0 = 0, oa1 = 0;
#pragma unroll
        for (int g = 0; g < 8; ++g) {
            oa0 += ho_red[g][lane];
            if (lane < 36) oa1 += ho_red[g][64 + lane];
        }
        bool o0 = false, o1 = false;
        lif(vo0, ro0, oa0, o0);
        if (lane < 36) lif(vo1, ro1, oa1, o1);
        const unsigned long long om0 = __ballot(o0);
        const unsigned long long om1 = __ballot(o1);
        if (o0) idx_o[__popcll(om0 & ((1ull << lane) - 1))] = (unsigned short)lane;
        if (o1) idx_o[__popcll(om0) + __popcll(om1 & ((1ull << lane) - 1))] =
            (unsigned short)(64 + lane);
        const int co = __popcll(om0) + __popcll(om1);
        if (lane < kNout) {
            const float yx = rowsum(idx_o, co, W_o, kNout, lane);
            bool ys = false;
            lif(vy, ry, yx, ys);
            out[((size_t)(kT - 1) * kB + b) * kNout + lane] = ys ? 1.0f : 0.0f;
        }
    }
}

extern "C" void kernel_launch(void* const* d_in, const int* in_sizes, int n_in,
                              void* d_out, int out_size, void* d_ws, size_t ws_size,
                              hipStream_t stream) {
    const float* x_in = (const float*)d_in[0];
    const float* W_i  = (const float*)d_in[1];
    const float* W_z  = (const float*)d_in[2];
    const float* W_c  = (const float*)d_in[3];
    const float* W_h  = (const float*)d_in[4];
    const float* W_ho = (const float*)d_in[5];
    const float* W_o  = (const float*)d_in[6];
    const float* lam  = (const float*)d_in[7];
    const float* eta  = (const float*)d_in[8];
    snn_seq<<<kB, 1024, 0, stream>>>(x_in, W_i, W_z, W_c, W_h, W_ho, W_o, lam, eta,
                                     (float*)d_out);
}